// Round 13
// baseline (807.561 us; speedup 1.0000x reference)
//
#include <hip/hip_runtime.h>
#include <hip/hip_bf16.h>
#include <stdint.h>

typedef unsigned short u16;
typedef __bf16 bf16x8 __attribute__((ext_vector_type(8)));
typedef float  f32x4  __attribute__((ext_vector_type(4)));
typedef u16    u16x8  __attribute__((ext_vector_type(8)));

__device__ __forceinline__ float bf2f(u16 u) {
    return __uint_as_float(((unsigned)u) << 16);
}
__device__ __forceinline__ u16 f2bf(float f) {   // round-to-nearest-even
    unsigned u = __float_as_uint(f);
    u += 0x7fffu + ((u >> 16) & 1u);
    return (u16)(u >> 16);
}
__device__ __forceinline__ u16x8 maxu16(u16x8 a, u16x8 b) {
    u16x8 r;
    #pragma unroll
    for (int e = 0; e < 8; ++e) r[e] = a[e] > b[e] ? a[e] : b[e];
    return r;
}

#define MFMA16(a, b, c) __builtin_amdgcn_mfma_f32_16x16x32_bf16(a, b, c, 0, 0, 0)

// Static device buffers — no d_ws dependency.
__device__ u16   h2g_buf[262144 * 64];            // h2 [N][64] bf16, row-major
__device__ u16   hc_buf[(size_t)262144 * 192];    // TILED [tile][c][r][8] (100.7 MB)
__device__ u16   w3b[64 * 64];
__device__ u16   w4b[128 * 64];
__device__ u16   w5b[1024 * 192];                 // TILED [bn][c][r][8]
__device__ float g_buf[1024];                     // global column max (>= 0)
__device__ float f1_buf[512];
__device__ float f2_buf[256];

// hc tiled address (u16 index) for point p, K-chunk c (c=0..23, 8 cols each)
// tile stride = 3072 CHUNKS (128 rows x 24 chunks); x8 converts chunk->u16.
__device__ __forceinline__ size_t hcAddr(size_t p, int c) {
    return ((p >> 7) * 3072 + (size_t)c * 128 + (p & 127)) * 8;
}

// ---------------------------------------------------------------------------
// kcvt: w3/w4 -> bf16; w5 -> bf16 tiled [bn][c][r][8]; zero g_buf.
// ---------------------------------------------------------------------------
__global__ void kcvt(const float* __restrict__ w3f, const float* __restrict__ w4f,
                     const float* __restrict__ w5f)
{
    int i = blockIdx.x * 256 + threadIdx.x;
    if (i < 1024) g_buf[i] = 0.f;
    if (i < 4096)        w3b[i]        = f2bf(w3f[i]);
    else if (i < 12288)  w4b[i - 4096] = f2bf(w4f[i - 4096]);
    else {
        int t = i - 12288;                 // 0..196607
        int e = t & 7, j = t >> 3;         // j = bn*3072 + c*128 + r
        int bn = j / 3072, rem = j - bn * 3072, c = rem >> 7, r = rem & 127;
        w5b[t] = f2bf(w5f[(size_t)(bn * 128 + r) * 192 + c * 8 + e]);
    }
}

// ---------------------------------------------------------------------------
// k1: mlp1..mlp4 for 64 points/block. h1(VALU) -> h2(-> h2g_buf row-major)
//     -> h3 -> h4 (-> hc_buf tiled, chunks 8..23).
// ---------------------------------------------------------------------------
__global__ __launch_bounds__(256) void k1_mlp(
    const float* __restrict__ xf, const float* __restrict__ w1f,
    const float* __restrict__ w2f)
{
    __shared__ __align__(16) u16 sw1[64 * 4];
    __shared__ __align__(16) u16 sx [64 * 4];
    __shared__ __align__(16) u16 sw2[64 * 72];
    __shared__ __align__(16) u16 shA[64 * 72];    // h1, then h3
    __shared__ __align__(16) u16 sh2[64 * 72];
    __shared__ __align__(16) u16 sh4[64 * 136];

    const int tid = threadIdx.x;
    const int p0  = blockIdx.x * 64;

    for (int i = tid; i < 64 * 64; i += 256)
        sw2[(i >> 6) * 72 + (i & 63)] = f2bf(w2f[i]);
    if (tid < 192) {
        sw1[(tid / 3) * 4 + tid % 3] = f2bf(w1f[tid]);
        sx [(tid / 3) * 4 + tid % 3] = f2bf(xf[p0 * 3 + tid]);
    }
    __syncthreads();

    {   // L1 via VALU (K=3)
        int m = tid & 63, ng = tid >> 6;
        float x0 = bf2f(sx[m * 4]), x1 = bf2f(sx[m * 4 + 1]), x2 = bf2f(sx[m * 4 + 2]);
        #pragma unroll
        for (int j = 0; j < 16; ++j) {
            int n = ng * 16 + j;
            float s = x0 * bf2f(sw1[n * 4]) + x1 * bf2f(sw1[n * 4 + 1]) + x2 * bf2f(sw1[n * 4 + 2]);
            shA[m * 72 + n] = f2bf(fmaxf(s, 0.f));
        }
    }
    __syncthreads();

    const int lane = tid & 63, w = tid >> 6, q = lane >> 4, l15 = lane & 15;
    const int mrow = 16 * w;

    // ---- L2: h2 -> sh2 ----
    {
        f32x4 acc[4];
        #pragma unroll
        for (int nt = 0; nt < 4; ++nt) acc[nt] = (f32x4){0.f, 0.f, 0.f, 0.f};
        #pragma unroll
        for (int ss = 0; ss < 2; ++ss) {
            bf16x8 a = *(const bf16x8*)&shA[(mrow + l15) * 72 + ss * 32 + q * 8];
            #pragma unroll
            for (int nt = 0; nt < 4; ++nt) {
                bf16x8 b = *(const bf16x8*)&sw2[(nt * 16 + l15) * 72 + ss * 32 + q * 8];
                acc[nt] = MFMA16(a, b, acc[nt]);
            }
        }
        #pragma unroll
        for (int nt = 0; nt < 4; ++nt)
            #pragma unroll
            for (int r = 0; r < 4; ++r)
                sh2[(mrow + q * 4 + r) * 72 + nt * 16 + l15] = f2bf(fmaxf(acc[nt][r], 0.f));
    }

    // ---- L3: h3 -> shA (wave-local rows) ----
    {
        f32x4 acc[4];
        #pragma unroll
        for (int nt = 0; nt < 4; ++nt) acc[nt] = (f32x4){0.f, 0.f, 0.f, 0.f};
        #pragma unroll
        for (int ss = 0; ss < 2; ++ss) {
            bf16x8 a = *(const bf16x8*)&sh2[(mrow + l15) * 72 + ss * 32 + q * 8];
            #pragma unroll
            for (int nt = 0; nt < 4; ++nt) {
                bf16x8 b = *(const bf16x8*)&w3b[(nt * 16 + l15) * 64 + ss * 32 + q * 8];
                acc[nt] = MFMA16(a, b, acc[nt]);
            }
        }
        #pragma unroll
        for (int nt = 0; nt < 4; ++nt)
            #pragma unroll
            for (int r = 0; r < 4; ++r)
                shA[(mrow + q * 4 + r) * 72 + nt * 16 + l15] = f2bf(fmaxf(acc[nt][r], 0.f));
    }

    // ---- L4: h4 -> sh4 ----
    {
        f32x4 acc[8];
        #pragma unroll
        for (int nt = 0; nt < 8; ++nt) acc[nt] = (f32x4){0.f, 0.f, 0.f, 0.f};
        #pragma unroll
        for (int ss = 0; ss < 2; ++ss) {
            bf16x8 a = *(const bf16x8*)&shA[(mrow + l15) * 72 + ss * 32 + q * 8];
            #pragma unroll
            for (int nt = 0; nt < 8; ++nt) {
                bf16x8 b = *(const bf16x8*)&w4b[(nt * 16 + l15) * 64 + ss * 32 + q * 8];
                acc[nt] = MFMA16(a, b, acc[nt]);
            }
        }
        #pragma unroll
        for (int nt = 0; nt < 8; ++nt)
            #pragma unroll
            for (int r = 0; r < 4; ++r)
                sh4[(mrow + q * 4 + r) * 136 + nt * 16 + l15] = f2bf(fmaxf(acc[nt][r], 0.f));
    }
    __syncthreads();

    {   // stores: h2 row-major; h4 -> tiled hc chunks 8..23
        int row = tid >> 2, c = (tid & 3) * 16;
        *(u16x8*)&h2g_buf[(size_t)p0 * 64 + tid * 16]     = *(const u16x8*)&sh2[row * 72 + c];
        *(u16x8*)&h2g_buf[(size_t)p0 * 64 + tid * 16 + 8] = *(const u16x8*)&sh2[row * 72 + c + 8];
        size_t p = (size_t)p0 + row;
        #pragma unroll
        for (int i = 0; i < 4; ++i) {
            int ch = 8 + (tid & 3) * 4 + i;
            *(u16x8*)&hc_buf[hcAddr(p, ch)] =
                *(const u16x8*)&sh4[row * 136 + (tid & 3) * 32 + i * 8];
        }
    }
}

// ---------------------------------------------------------------------------
// k2_pool: 8 threads per point. 16 independent row-gathers in flight,
//   packed-u16 max (post-relu bf16 >= 0), writes hc tiled chunks 0..7.
// ---------------------------------------------------------------------------
__global__ __launch_bounds__(256) void k2_pool(const int* __restrict__ idx)
{
    const size_t gt = (size_t)blockIdx.x * 256 + threadIdx.x;
    const size_t p  = gt >> 3;
    const int    cn = threadIdx.x & 7;

    u16x8 v[16];
    #pragma unroll
    for (int k = 0; k < 16; ++k) {
        int j = idx[p * 16 + k];
        v[k] = *(const u16x8*)&h2g_buf[(size_t)j * 64 + cn * 8];
    }
    u16x8 m = v[0];
    #pragma unroll
    for (int k = 1; k < 16; ++k) m = maxu16(m, v[k]);
    *(u16x8*)&hc_buf[hcAddr(p, cn)] = m;
}

// ---------------------------------------------------------------------------
// k3_gemm helpers
// ---------------------------------------------------------------------------
__device__ __forceinline__ void loadA(bf16x8 (&dst)[2][4], int t, int kt,
                                      int q, int m0w, int l15)
{
    #pragma unroll
    for (int ss = 0; ss < 2; ++ss)
        #pragma unroll
        for (int mt = 0; mt < 4; ++mt)
            dst[ss][mt] = *(const bf16x8*)&hc_buf[((size_t)t * 3072 +
                (size_t)((kt * 8 + ss * 4 + q) * 128 + m0w + mt * 16 + l15)) * 8];
}
__device__ __forceinline__ void mmaKt(f32x4 (&acc)[4][4], const bf16x8 (&a)[2][4],
                                      const bf16x8 (&b)[2][4])
{
    #pragma unroll
    for (int ss = 0; ss < 2; ++ss)
        #pragma unroll
        for (int mt = 0; mt < 4; ++mt)
            #pragma unroll
            for (int nt = 0; nt < 4; ++nt)
                acc[mt][nt] = MFMA16(a[ss][mt], b[ss][nt], acc[mt][nt]);
}
// one m-tile: enters with kt0 frags in aCur, exits with next-tile kt0 in aNxt
__device__ __forceinline__ void tileStep(
    float (&mx)[4], bf16x8 (&aCur)[2][4], bf16x8 (&aNxt)[2][4],
    const bf16x8 (&breg)[3][2][4], int t, int tn, int q, int m0w, int l15)
{
    f32x4 acc[4][4];
    #pragma unroll
    for (int mt = 0; mt < 4; ++mt)
        #pragma unroll
        for (int nt = 0; nt < 4; ++nt) acc[mt][nt] = (f32x4){0.f, 0.f, 0.f, 0.f};
    loadA(aNxt, t, 1, q, m0w, l15);
    mmaKt(acc, aCur, breg[0]);
    loadA(aCur, t, 2, q, m0w, l15);
    mmaKt(acc, aNxt, breg[1]);
    loadA(aNxt, tn, 0, q, m0w, l15);
    mmaKt(acc, aCur, breg[2]);
    #pragma unroll
    for (int nt = 0; nt < 4; ++nt)
        #pragma unroll
        for (int mt = 0; mt < 4; ++mt)
            #pragma unroll
            for (int r = 0; r < 4; ++r) mx[nt] = fmaxf(mx[nt], acc[mt][nt][r]);
}

// ---------------------------------------------------------------------------
// k3_gemm: one block = (bn, 8 m-tiles). No LDS, no barriers. All 24 B-frags
//   in VGPRs (pre-tiled w5b, L2-resident); A-frags double-buffered per kt
//   from tiled hc (4x256B coalesced). Column max in regs across m-tiles;
//   one atomicMax set per block (relu folded into 0-init, values >= 0).
//   XCD map: xcd=i&7 owns mgroups xcd*32.. -> all 8 bn of an mgroup on one
//   XCD, adjacent in dispatch -> A re-reads hit per-XCD L2.
// ---------------------------------------------------------------------------
__global__ __launch_bounds__(256, 2) void k3_gemm(int* __restrict__ g)
{
    const int tid  = threadIdx.x;
    const int lane = tid & 63, w = tid >> 6, q = lane >> 4, l15 = lane & 15;
    const int m0w  = (w & 1) * 64, n0w = (w >> 1) * 64;

    const int i  = blockIdx.x;
    const int j  = i >> 3;
    const int bn = j & 7;
    const int mg = (i & 7) * 32 + (j >> 3);    // mgroup 0..255
    const int tIdx = mg * 8;

    bf16x8 breg[3][2][4];
    #pragma unroll
    for (int kt = 0; kt < 3; ++kt)
        #pragma unroll
        for (int ss = 0; ss < 2; ++ss)
            #pragma unroll
            for (int nt = 0; nt < 4; ++nt)
                breg[kt][ss][nt] = *(const bf16x8*)&w5b[
                    ((size_t)bn * 3072 +
                     (size_t)((kt * 8 + ss * 4 + q) * 128 + n0w + nt * 16 + l15)) * 8];

    bf16x8 aA[2][4], aB[2][4];
    loadA(aA, tIdx, 0, q, m0w, l15);

    float mx[4] = {0.f, 0.f, 0.f, 0.f};
    #pragma unroll
    for (int pair = 0; pair < 4; ++pair) {
        int t0 = tIdx + 2 * pair;
        tileStep(mx, aA, aB, breg, t0,     t0 + 1,                       q, m0w, l15);
        tileStep(mx, aB, aA, breg, t0 + 1, (pair < 3) ? t0 + 2 : t0 + 1, q, m0w, l15);
    }

    #pragma unroll
    for (int nt = 0; nt < 4; ++nt) {
        float m = mx[nt];
        m = fmaxf(m, __shfl_xor(m, 16, 64));
        m = fmaxf(m, __shfl_xor(m, 32, 64));
        if (q == 0) {
            int col = bn * 128 + n0w + nt * 16 + l15;
            atomicMax(&g[col], __float_as_int(m));
        }
    }
}

// ---------------------------------------------------------------------------
// k4: classifier head, pure f32. One wave per output row.
// ---------------------------------------------------------------------------
__global__ void k4_f1(const float* __restrict__ wf1)
{
    int r = blockIdx.x, l = threadIdx.x;
    float s = 0.f;
    #pragma unroll
    for (int i = 0; i < 16; ++i) s += wf1[r * 1024 + i * 64 + l] * g_buf[i * 64 + l];
    #pragma unroll
    for (int o = 32; o; o >>= 1) s += __shfl_down(s, o, 64);
    if (!l) f1_buf[r] = fmaxf(s, 0.f);
}
__global__ void k4_f2(const float* __restrict__ wf2)
{
    int r = blockIdx.x, l = threadIdx.x;
    float s = 0.f;
    #pragma unroll
    for (int i = 0; i < 8; ++i) s += wf2[r * 512 + i * 64 + l] * f1_buf[i * 64 + l];
    #pragma unroll
    for (int o = 32; o; o >>= 1) s += __shfl_down(s, o, 64);
    if (!l) f2_buf[r] = fmaxf(s, 0.f);
}
__global__ void k4_out(const float* __restrict__ wf3, float* __restrict__ out)
{
    int r = blockIdx.x, l = threadIdx.x;
    float s = 0.f;
    #pragma unroll
    for (int i = 0; i < 4; ++i) s += wf3[r * 256 + i * 64 + l] * f2_buf[i * 64 + l];
    #pragma unroll
    for (int o = 32; o; o >>= 1) s += __shfl_down(s, o, 64);
    if (!l) out[r] = s;
}

// ---------------------------------------------------------------------------
extern "C" void kernel_launch(void* const* d_in, const int* in_sizes, int n_in,
                              void* d_out, int out_size, void* d_ws, size_t ws_size,
                              hipStream_t stream)
{
    (void)in_sizes; (void)n_in; (void)out_size; (void)d_ws; (void)ws_size;
    const float* x   = (const float*)d_in[0];
    const int*   idx = (const int*)d_in[2];
    const float* w1  = (const float*)d_in[3];
    const float* w2  = (const float*)d_in[4];
    const float* w3  = (const float*)d_in[5];
    const float* w4  = (const float*)d_in[6];
    const float* w5  = (const float*)d_in[7];
    const float* wf1 = (const float*)d_in[8];
    const float* wf2 = (const float*)d_in[9];
    const float* wf3 = (const float*)d_in[10];

    float* gptr;
    hipGetSymbolAddress((void**)&gptr, HIP_SYMBOL(g_buf));

    kcvt   <<<816, 256, 0, stream>>>(w3, w4, w5);
    k1_mlp <<<262144 / 64, 256, 0, stream>>>(x, w1, w2);
    k2_pool<<<262144 * 8 / 256, 256, 0, stream>>>(idx);
    k3_gemm<<<2048, 256, 0, stream>>>((int*)gptr);
    k4_f1  <<<512, 64, 0, stream>>>(wf1);
    k4_f2  <<<256, 64, 0, stream>>>(wf2);
    k4_out <<<40, 64, 0, stream>>>(wf3, (float*)d_out);
}

// Round 14
// 464.332 us; speedup vs baseline: 1.7392x; 1.7392x over previous
//
#include <hip/hip_runtime.h>
#include <hip/hip_bf16.h>
#include <stdint.h>

typedef unsigned short u16;
typedef __bf16 bf16x8 __attribute__((ext_vector_type(8)));
typedef float  f32x4  __attribute__((ext_vector_type(4)));
typedef u16    u16x8  __attribute__((ext_vector_type(8)));

__device__ __forceinline__ float bf2f(u16 u) {
    return __uint_as_float(((unsigned)u) << 16);
}
__device__ __forceinline__ u16 f2bf(float f) {   // round-to-nearest-even
    unsigned u = __float_as_uint(f);
    u += 0x7fffu + ((u >> 16) & 1u);
    return (u16)(u >> 16);
}
__device__ __forceinline__ u16x8 maxu16(u16x8 a, u16x8 b) {
    u16x8 r;
    #pragma unroll
    for (int e = 0; e < 8; ++e) r[e] = a[e] > b[e] ? a[e] : b[e];
    return r;
}

#define MFMA16(a, b, c) __builtin_amdgcn_mfma_f32_16x16x32_bf16(a, b, c, 0, 0, 0)

// Static device buffers — no d_ws dependency.
__device__ u16   h2g_buf[262144 * 64];            // h2 [N][64] bf16, row-major
__device__ u16   hc_buf[(size_t)262144 * 192];    // TILED [tile][c][r][8] (100.7 MB)
__device__ u16   w3b[64 * 64];
__device__ u16   w4b[128 * 64];
__device__ u16   w5b[1024 * 192];                 // TILED [bn][c][r][8]
__device__ float g_buf[1024];                     // global column max (>= 0)
__device__ float f1_buf[512];
__device__ float f2_buf[256];

// hc tiled address (u16 index) for point p, K-chunk c (c=0..23, 8 cols each)
// tile stride = 3072 CHUNKS (128 rows x 24 chunks); x8 converts chunk->u16.
__device__ __forceinline__ size_t hcAddr(size_t p, int c) {
    return ((p >> 7) * 3072 + (size_t)c * 128 + (p & 127)) * 8;
}

// ---------------------------------------------------------------------------
// kcvt: w3/w4 -> bf16; w5 -> bf16 tiled [bn][c][r][8]; zero g_buf.
// ---------------------------------------------------------------------------
__global__ void kcvt(const float* __restrict__ w3f, const float* __restrict__ w4f,
                     const float* __restrict__ w5f)
{
    int i = blockIdx.x * 256 + threadIdx.x;
    if (i < 1024) g_buf[i] = 0.f;
    if (i < 4096)        w3b[i]        = f2bf(w3f[i]);
    else if (i < 12288)  w4b[i - 4096] = f2bf(w4f[i - 4096]);
    else {
        int t = i - 12288;                 // 0..196607
        int e = t & 7, j = t >> 3;         // j = bn*3072 + c*128 + r
        int bn = j / 3072, rem = j - bn * 3072, c = rem >> 7, r = rem & 127;
        w5b[t] = f2bf(w5f[(size_t)(bn * 128 + r) * 192 + c * 8 + e]);
    }
}

// ---------------------------------------------------------------------------
// k1: mlp1..mlp4 for 64 points/block. h1(VALU) -> h2(-> h2g_buf row-major)
//     -> h3 -> h4 (-> hc_buf tiled, chunks 8..23).
// ---------------------------------------------------------------------------
__global__ __launch_bounds__(256) void k1_mlp(
    const float* __restrict__ xf, const float* __restrict__ w1f,
    const float* __restrict__ w2f)
{
    __shared__ __align__(16) u16 sw1[64 * 4];
    __shared__ __align__(16) u16 sx [64 * 4];
    __shared__ __align__(16) u16 sw2[64 * 72];
    __shared__ __align__(16) u16 shA[64 * 72];    // h1, then h3
    __shared__ __align__(16) u16 sh2[64 * 72];
    __shared__ __align__(16) u16 sh4[64 * 136];

    const int tid = threadIdx.x;
    const int p0  = blockIdx.x * 64;

    for (int i = tid; i < 64 * 64; i += 256)
        sw2[(i >> 6) * 72 + (i & 63)] = f2bf(w2f[i]);
    if (tid < 192) {
        sw1[(tid / 3) * 4 + tid % 3] = f2bf(w1f[tid]);
        sx [(tid / 3) * 4 + tid % 3] = f2bf(xf[p0 * 3 + tid]);
    }
    __syncthreads();

    {   // L1 via VALU (K=3)
        int m = tid & 63, ng = tid >> 6;
        float x0 = bf2f(sx[m * 4]), x1 = bf2f(sx[m * 4 + 1]), x2 = bf2f(sx[m * 4 + 2]);
        #pragma unroll
        for (int j = 0; j < 16; ++j) {
            int n = ng * 16 + j;
            float s = x0 * bf2f(sw1[n * 4]) + x1 * bf2f(sw1[n * 4 + 1]) + x2 * bf2f(sw1[n * 4 + 2]);
            shA[m * 72 + n] = f2bf(fmaxf(s, 0.f));
        }
    }
    __syncthreads();

    const int lane = tid & 63, w = tid >> 6, q = lane >> 4, l15 = lane & 15;
    const int mrow = 16 * w;

    // ---- L2: h2 -> sh2 ----
    {
        f32x4 acc[4];
        #pragma unroll
        for (int nt = 0; nt < 4; ++nt) acc[nt] = (f32x4){0.f, 0.f, 0.f, 0.f};
        #pragma unroll
        for (int ss = 0; ss < 2; ++ss) {
            bf16x8 a = *(const bf16x8*)&shA[(mrow + l15) * 72 + ss * 32 + q * 8];
            #pragma unroll
            for (int nt = 0; nt < 4; ++nt) {
                bf16x8 b = *(const bf16x8*)&sw2[(nt * 16 + l15) * 72 + ss * 32 + q * 8];
                acc[nt] = MFMA16(a, b, acc[nt]);
            }
        }
        #pragma unroll
        for (int nt = 0; nt < 4; ++nt)
            #pragma unroll
            for (int r = 0; r < 4; ++r)
                sh2[(mrow + q * 4 + r) * 72 + nt * 16 + l15] = f2bf(fmaxf(acc[nt][r], 0.f));
    }

    // ---- L3: h3 -> shA (wave-local rows) ----
    {
        f32x4 acc[4];
        #pragma unroll
        for (int nt = 0; nt < 4; ++nt) acc[nt] = (f32x4){0.f, 0.f, 0.f, 0.f};
        #pragma unroll
        for (int ss = 0; ss < 2; ++ss) {
            bf16x8 a = *(const bf16x8*)&sh2[(mrow + l15) * 72 + ss * 32 + q * 8];
            #pragma unroll
            for (int nt = 0; nt < 4; ++nt) {
                bf16x8 b = *(const bf16x8*)&w3b[(nt * 16 + l15) * 64 + ss * 32 + q * 8];
                acc[nt] = MFMA16(a, b, acc[nt]);
            }
        }
        #pragma unroll
        for (int nt = 0; nt < 4; ++nt)
            #pragma unroll
            for (int r = 0; r < 4; ++r)
                shA[(mrow + q * 4 + r) * 72 + nt * 16 + l15] = f2bf(fmaxf(acc[nt][r], 0.f));
    }

    // ---- L4: h4 -> sh4 ----
    {
        f32x4 acc[8];
        #pragma unroll
        for (int nt = 0; nt < 8; ++nt) acc[nt] = (f32x4){0.f, 0.f, 0.f, 0.f};
        #pragma unroll
        for (int ss = 0; ss < 2; ++ss) {
            bf16x8 a = *(const bf16x8*)&shA[(mrow + l15) * 72 + ss * 32 + q * 8];
            #pragma unroll
            for (int nt = 0; nt < 8; ++nt) {
                bf16x8 b = *(const bf16x8*)&w4b[(nt * 16 + l15) * 64 + ss * 32 + q * 8];
                acc[nt] = MFMA16(a, b, acc[nt]);
            }
        }
        #pragma unroll
        for (int nt = 0; nt < 8; ++nt)
            #pragma unroll
            for (int r = 0; r < 4; ++r)
                sh4[(mrow + q * 4 + r) * 136 + nt * 16 + l15] = f2bf(fmaxf(acc[nt][r], 0.f));
    }
    __syncthreads();

    {   // stores: h2 row-major; h4 -> tiled hc chunks 8..23
        int row = tid >> 2, c = (tid & 3) * 16;
        *(u16x8*)&h2g_buf[(size_t)p0 * 64 + tid * 16]     = *(const u16x8*)&sh2[row * 72 + c];
        *(u16x8*)&h2g_buf[(size_t)p0 * 64 + tid * 16 + 8] = *(const u16x8*)&sh2[row * 72 + c + 8];
        size_t p = (size_t)p0 + row;
        #pragma unroll
        for (int i = 0; i < 4; ++i) {
            int ch = 8 + (tid & 3) * 4 + i;
            *(u16x8*)&hc_buf[hcAddr(p, ch)] =
                *(const u16x8*)&sh4[row * 136 + (tid & 3) * 32 + i * 8];
        }
    }
}

// ---------------------------------------------------------------------------
// k2_pool: 8 threads per point. 16 independent row-gathers in flight,
//   packed-u16 max (post-relu bf16 >= 0), writes hc tiled chunks 0..7.
// ---------------------------------------------------------------------------
__global__ __launch_bounds__(256) void k2_pool(const int* __restrict__ idx)
{
    const size_t gt = (size_t)blockIdx.x * 256 + threadIdx.x;
    const size_t p  = gt >> 3;
    const int    cn = threadIdx.x & 7;

    u16x8 v[16];
    #pragma unroll
    for (int k = 0; k < 16; ++k) {
        int j = idx[p * 16 + k];
        v[k] = *(const u16x8*)&h2g_buf[(size_t)j * 64 + cn * 8];
    }
    u16x8 m = v[0];
    #pragma unroll
    for (int k = 1; k < 16; ++k) m = maxu16(m, v[k]);
    *(u16x8*)&hc_buf[hcAddr(p, cn)] = m;
}

// ---------------------------------------------------------------------------
// k3_gemm helpers
// ---------------------------------------------------------------------------
__device__ __forceinline__ void loadA(bf16x8 (&dst)[2][4], int t, int kt,
                                      int q, int m0w, int l15)
{
    #pragma unroll
    for (int ss = 0; ss < 2; ++ss)
        #pragma unroll
        for (int mt = 0; mt < 4; ++mt)
            dst[ss][mt] = *(const bf16x8*)&hc_buf[((size_t)t * 3072 +
                (size_t)((kt * 8 + ss * 4 + q) * 128 + m0w + mt * 16 + l15)) * 8];
}
__device__ __forceinline__ void mmaKt(f32x4 (&acc)[4][4], const bf16x8 (&a)[2][4],
                                      const bf16x8 (&b)[2][4])
{
    #pragma unroll
    for (int ss = 0; ss < 2; ++ss)
        #pragma unroll
        for (int mt = 0; mt < 4; ++mt)
            #pragma unroll
            for (int nt = 0; nt < 4; ++nt)
                acc[mt][nt] = MFMA16(a[ss][mt], b[ss][nt], acc[mt][nt]);
}
// one m-tile: enters with kt0 frags in aCur, exits with next-tile kt0 in aNxt
__device__ __forceinline__ void tileStep(
    float (&mx)[4], bf16x8 (&aCur)[2][4], bf16x8 (&aNxt)[2][4],
    const bf16x8 (&breg)[3][2][4], int t, int tn, int q, int m0w, int l15)
{
    f32x4 acc[4][4];
    #pragma unroll
    for (int mt = 0; mt < 4; ++mt)
        #pragma unroll
        for (int nt = 0; nt < 4; ++nt) acc[mt][nt] = (f32x4){0.f, 0.f, 0.f, 0.f};
    loadA(aNxt, t, 1, q, m0w, l15);
    mmaKt(acc, aCur, breg[0]);
    loadA(aCur, t, 2, q, m0w, l15);
    mmaKt(acc, aNxt, breg[1]);
    loadA(aNxt, tn, 0, q, m0w, l15);
    mmaKt(acc, aCur, breg[2]);
    #pragma unroll
    for (int nt = 0; nt < 4; ++nt)
        #pragma unroll
        for (int mt = 0; mt < 4; ++mt)
            #pragma unroll
            for (int r = 0; r < 4; ++r) mx[nt] = fmaxf(mx[nt], acc[mt][nt][r]);
}

// ---------------------------------------------------------------------------
// k3_gemm: one block = (bn, 8 m-tiles). No LDS, no barriers. All 24 B-frags
//   in VGPRs (pre-tiled w5b, L2-resident); A-frags double-buffered per kt
//   from tiled hc (4x256B coalesced). Column max in regs across m-tiles;
//   one atomicMax set per block (relu folded into 0-init, values >= 0).
//   NOTE: no min-waves in launch_bounds — needs ~240 VGPRs; capping at 128
//   (round 13) spilled 830 MB to scratch and ran 2x slower.
// ---------------------------------------------------------------------------
__global__ __launch_bounds__(256) void k3_gemm(int* __restrict__ g)
{
    const int tid  = threadIdx.x;
    const int lane = tid & 63, w = tid >> 6, q = lane >> 4, l15 = lane & 15;
    const int m0w  = (w & 1) * 64, n0w = (w >> 1) * 64;

    const int i  = blockIdx.x;
    const int j  = i >> 3;
    const int bn = j & 7;
    const int mg = (i & 7) * 32 + (j >> 3);    // mgroup 0..255
    const int tIdx = mg * 8;

    bf16x8 breg[3][2][4];
    #pragma unroll
    for (int kt = 0; kt < 3; ++kt)
        #pragma unroll
        for (int ss = 0; ss < 2; ++ss)
            #pragma unroll
            for (int nt = 0; nt < 4; ++nt)
                breg[kt][ss][nt] = *(const bf16x8*)&w5b[
                    ((size_t)bn * 3072 +
                     (size_t)((kt * 8 + ss * 4 + q) * 128 + n0w + nt * 16 + l15)) * 8];

    bf16x8 aA[2][4], aB[2][4];
    loadA(aA, tIdx, 0, q, m0w, l15);

    float mx[4] = {0.f, 0.f, 0.f, 0.f};
    #pragma unroll
    for (int pair = 0; pair < 4; ++pair) {
        int t0 = tIdx + 2 * pair;
        tileStep(mx, aA, aB, breg, t0,     t0 + 1,                       q, m0w, l15);
        tileStep(mx, aB, aA, breg, t0 + 1, (pair < 3) ? t0 + 2 : t0 + 1, q, m0w, l15);
    }

    #pragma unroll
    for (int nt = 0; nt < 4; ++nt) {
        float m = mx[nt];
        m = fmaxf(m, __shfl_xor(m, 16, 64));
        m = fmaxf(m, __shfl_xor(m, 32, 64));
        if (q == 0) {
            int col = bn * 128 + n0w + nt * 16 + l15;
            atomicMax(&g[col], __float_as_int(m));
        }
    }
}

// ---------------------------------------------------------------------------
// k4: classifier head, pure f32. One wave per output row.
// ---------------------------------------------------------------------------
__global__ void k4_f1(const float* __restrict__ wf1)
{
    int r = blockIdx.x, l = threadIdx.x;
    float s = 0.f;
    #pragma unroll
    for (int i = 0; i < 16; ++i) s += wf1[r * 1024 + i * 64 + l] * g_buf[i * 64 + l];
    #pragma unroll
    for (int o = 32; o; o >>= 1) s += __shfl_down(s, o, 64);
    if (!l) f1_buf[r] = fmaxf(s, 0.f);
}
__global__ void k4_f2(const float* __restrict__ wf2)
{
    int r = blockIdx.x, l = threadIdx.x;
    float s = 0.f;
    #pragma unroll
    for (int i = 0; i < 8; ++i) s += wf2[r * 512 + i * 64 + l] * f1_buf[i * 64 + l];
    #pragma unroll
    for (int o = 32; o; o >>= 1) s += __shfl_down(s, o, 64);
    if (!l) f2_buf[r] = fmaxf(s, 0.f);
}
__global__ void k4_out(const float* __restrict__ wf3, float* __restrict__ out)
{
    int r = blockIdx.x, l = threadIdx.x;
    float s = 0.f;
    #pragma unroll
    for (int i = 0; i < 4; ++i) s += wf3[r * 256 + i * 64 + l] * f2_buf[i * 64 + l];
    #pragma unroll
    for (int o = 32; o; o >>= 1) s += __shfl_down(s, o, 64);
    if (!l) out[r] = s;
}

// ---------------------------------------------------------------------------
extern "C" void kernel_launch(void* const* d_in, const int* in_sizes, int n_in,
                              void* d_out, int out_size, void* d_ws, size_t ws_size,
                              hipStream_t stream)
{
    (void)in_sizes; (void)n_in; (void)out_size; (void)d_ws; (void)ws_size;
    const float* x   = (const float*)d_in[0];
    const int*   idx = (const int*)d_in[2];
    const float* w1  = (const float*)d_in[3];
    const float* w2  = (const float*)d_in[4];
    const float* w3  = (const float*)d_in[5];
    const float* w4  = (const float*)d_in[6];
    const float* w5  = (const float*)d_in[7];
    const float* wf1 = (const float*)d_in[8];
    const float* wf2 = (const float*)d_in[9];
    const float* wf3 = (const float*)d_in[10];

    float* gptr;
    hipGetSymbolAddress((void**)&gptr, HIP_SYMBOL(g_buf));

    kcvt   <<<816, 256, 0, stream>>>(w3, w4, w5);
    k1_mlp <<<262144 / 64, 256, 0, stream>>>(x, w1, w2);
    k2_pool<<<262144 * 8 / 256, 256, 0, stream>>>(idx);
    k3_gemm<<<2048, 256, 0, stream>>>((int*)gptr);
    k4_f1  <<<512, 64, 0, stream>>>(wf1);
    k4_f2  <<<256, 64, 0, stream>>>(wf2);
    k4_out <<<40, 64, 0, stream>>>(wf3, (float*)d_out);
}